// Round 15
// baseline (15102.232 us; speedup 1.0000x reference)
//
#include <hip/hip_runtime.h>
#include <cmath>

typedef __attribute__((ext_vector_type(8))) short short8;
typedef __attribute__((ext_vector_type(4))) float f32x4;

#define B_SZ 512
#define T_SZ 256
#define I_SZ 256
#define H_SZ 1024
#define V_SZ 1024
#define E_SZ 8
#define FUT 64

// R5 numerics (3 products: A_hi*W_hi + A_hi*W_lo + A_lo*W_hi), paired W layout
// (R12, verified). NEW in R15: A buffers are FRAGMENT-MAJOR -- element
// (row, col) lives at tile (row>>4, col>>5), lane (row&15)+(((col>>3)&3)<<4),
// elem col&7; each MFMA af fragment is one coalesced 1KB global load (L2).
// A logical cols:
//   enc: [x_hi 256 | x_lo 256 | h_hi 1024 | h_lo 1024] = 2560 (KT=80)
//   dec: [xc 128 (x_hi8|x_hi8|x_lo8|0) | h_hi 1024 | h_lo 1024] = 2176 (KT=68)
// W packed (unchanged): paired [W_hi|W_lo] x128, then singles [W_hi] x64.
#define KVE 3840
#define KVD 3200
#define KVF 3072
#define APE 2560
#define APD 2176

static __device__ __forceinline__ ushort f2bf(float v) {
    uint32_t u = __float_as_uint(v);
    uint32_t r = (u + 0x7fffu + ((u >> 16) & 1u)) >> 16;
    return (ushort)r;
}
static __device__ __forceinline__ float bf2f(ushort b) {
    return __uint_as_float(((uint32_t)b) << 16);
}
// Monotone float->uint mapping: a > b  <=>  map(a) > map(b) (finite floats).
static __device__ __forceinline__ uint32_t fmono(float f) {
    uint32_t u = __float_as_uint(f);
    return (u & 0x80000000u) ? ~u : (u | 0x80000000u);
}
template<int N>
static __device__ __forceinline__ void waitvm() {
    if constexpr (N == 0)      asm volatile("s_waitcnt vmcnt(0)" ::: "memory");
    else if constexpr (N == 2) asm volatile("s_waitcnt vmcnt(2)" ::: "memory");
    else if constexpr (N == 3) asm volatile("s_waitcnt vmcnt(3)" ::: "memory");
    else if constexpr (N == 4) asm volatile("s_waitcnt vmcnt(4)" ::: "memory");
    else if constexpr (N == 6) asm volatile("s_waitcnt vmcnt(6)" ::: "memory");
    else if constexpr (N == 8) asm volatile("s_waitcnt vmcnt(8)" ::: "memory");
}

#define GLD16(gp, lp)                                                          \
    __builtin_amdgcn_global_load_lds(                                         \
        (const __attribute__((address_space(1))) void*)(gp),                  \
        (__attribute__((address_space(3))) void*)(lp), 16, 0, 0)

// ---------------------------------------------------------------------------
// Paired split-bf16 GEMM step, fragment-major A. Block (MFR*32) x (NFR*32),
// 4 waves (2m x 2n). W is LDS-staged (3 rotating buffers, XOR-swizzled);
// A fragments load DIRECTLY from global (fragment-major: one coalesced
// dwordx4 per wave per fragment) into 3 rotating register sets, issued with
// the W stage 2 tiles ahead. Counted-vmcnt pipeline: group(i) = W-loads
// (2*NFR paired / NFR single) + af-loads (2*MFR); wait before compute(i)
// leaves only group(i+1) outstanding. Loads cannot cross the memory-clobber
// waitvm asm, so group issue-order (and thus in-order vmcnt retirement) is
// pinned.
// ---------------------------------------------------------------------------
template<int MFR, int NFR, int NTPX,
         int NKP, int PT1, int PO0, int PO1,
         int NKS, int ST1, int SO0, int SO1, bool GATES>
__global__ __launch_bounds__(256) void gemm_step(
    const ushort* __restrict__ A, int astr,
    const ushort* __restrict__ W, int kv,
    const float* __restrict__ bias,
    float* __restrict__ c,
    ushort* __restrict__ hdest, int hoff, int hkt,
    const float* __restrict__ xsrc, ushort* __restrict__ xdest,
    float* __restrict__ out, int ldo,
    unsigned long long* __restrict__ keys)
{
    constexpr int WBUF = NFR * 4096;             // ushorts per W buffer (pair)
    __shared__ __align__(16) ushort lds[3 * WBUF];

    const int tid = threadIdx.x;
    const int lane = tid & 63;
    const int wid = tid >> 6;
    const int wm = wid >> 1, wn = wid & 1;
    const int l15 = lane & 15, lq = lane >> 4;
    const int l7 = lane & 7, l3 = lane >> 3;

    const int flat = blockIdx.x;
    const int xcd = flat & 7, slot = flat >> 3;
    const int n_tile = xcd * NTPX + (slot % NTPX);
    const int m_tile = slot / NTPX;
    const int m0 = m_tile * (MFR * 32);
    const int n0 = n_tile * (NFR * 32);
    const int KT = astr >> 5;                    // A k-tiles per row-tile

    f32x4 acc[MFR][NFR];
#pragma unroll
    for (int m = 0; m < MFR; ++m)
#pragma unroll
        for (int n = 0; n < NFR; ++n) { f32x4 z = {0.f, 0.f, 0.f, 0.f}; acc[m][n] = z; }

    auto stageWP = [&](int p, int bufi) {        // W pair-tile: 64 x 128
        const int kcW = p * 128;
        ushort* wb = &lds[bufi * WBUF];
#pragma unroll
        for (int i = 0; i < 2 * NFR; ++i) {      // 256B rows, 16 lanes/row
            const int rowg = (i * 4 + wid) * 4;
            const int row = rowg + lq;
            GLD16(W + (size_t)(n0 + row) * kv + kcW + ((l15 ^ (row & 15)) * 8),
                  wb + rowg * 128);
        }
    };
    auto stageWS = [&](int s, int bufi) {        // W single tile: 64 x 64
        const int kcW = NKP * 128 + s * 64;
        ushort* wb = &lds[bufi * WBUF];
#pragma unroll
        for (int i = 0; i < NFR; ++i) {          // 128B rows
            const int rowg = (i * 4 + wid) * 8;
            const int row = rowg + l3;
            GLD16(W + (size_t)(n0 + row) * kv + kcW + ((l7 ^ (row & 7)) * 8),
                  wb + rowg * 64);
        }
    };
    // af fragments for tile i -> registers (fragment-major A, coalesced).
    auto AFL = [&](int i, short8 (&dst)[MFR][2]) {
        int kcA;
        if (i < NKP) kcA = i * 64 + (i < PT1 ? PO0 : PO1);
        else { const int s = i - NKP; kcA = s * 64 + (s < ST1 ? SO0 : SO1); }
        const int ktb = kcA >> 5;
#pragma unroll
        for (int m = 0; m < MFR; ++m) {
            const int rt = (m0 + wm * (MFR * 16) + m * 16) >> 4;
#pragma unroll
            for (int kk = 0; kk < 2; ++kk)
                dst[m][kk] = *(const short8*)
                    &A[(((size_t)rt * KT + ktb + kk) * 64 + lane) * 8];
        }
    };
    auto compP = [&](int bufi, const short8 (&af)[MFR][2]) {
        const ushort* wb = &lds[bufi * WBUF];
#pragma unroll
        for (int kk = 0; kk < 2; ++kk) {
#pragma unroll
            for (int sub = 0; sub < 2; ++sub) {
                short8 wf[NFR];
#pragma unroll
                for (int n = 0; n < NFR; ++n) {
                    const int row = wn * (NFR * 16) + n * 16 + l15;
                    wf[n] = *(const short8*)
                        &wb[row * 128 + (((sub * 8 + kk * 4 + lq) ^ (row & 15)) * 8)];
                }
#pragma unroll
                for (int m = 0; m < MFR; ++m)
#pragma unroll
                    for (int n = 0; n < NFR; ++n)
                        acc[m][n] = __builtin_amdgcn_mfma_f32_16x16x32_bf16(
                            af[m][kk], wf[n], acc[m][n], 0, 0, 0);
            }
        }
    };
    auto compS = [&](int bufi, const short8 (&af)[MFR][2]) {
        const ushort* wb = &lds[bufi * WBUF];
#pragma unroll
        for (int kk = 0; kk < 2; ++kk) {
            short8 wf[NFR];
#pragma unroll
            for (int n = 0; n < NFR; ++n) {
                const int row = wn * (NFR * 16) + n * 16 + l15;
                wf[n] = *(const short8*)
                    &wb[row * 64 + (((kk * 4 + lq) ^ (row & 7)) * 8)];
            }
#pragma unroll
            for (int m = 0; m < MFR; ++m)
#pragma unroll
                for (int n = 0; n < NFR; ++n)
                    acc[m][n] = __builtin_amdgcn_mfma_f32_16x16x32_bf16(
                        af[m][kk], wf[n], acc[m][n], 0, 0, 0);
        }
    };

    auto STGW = [&](int i, int b) { if (i < NKP) stageWP(i, b); else stageWS(i - NKP, b); };

    constexpr int NT = NKP + NKS;

    short8 afs[3][MFR][2];
    STGW(0, 0); AFL(0, afs[0]);
    STGW(1, 1); AFL(1, afs[1]);
#pragma unroll 1
    for (int i0 = 0; i0 < NT; i0 += 3) {
#pragma unroll
        for (int j = 0; j < 3; ++j) {
            const int i = i0 + j;
            if (i < NT) {
                // wait: group i done; outstanding = group i+1 only.
                if (i + 1 < NKP)     waitvm<2 * NFR + 2 * MFR>();
                else if (i + 1 < NT) waitvm<NFR + 2 * MFR>();
                else                 waitvm<0>();
                __builtin_amdgcn_s_barrier();
                if (i + 2 < NT) { STGW(i + 2, (j + 2) % 3); AFL(i + 2, afs[(j + 2) % 3]); }
                if (i < NKP) compP(j, afs[j]); else compS(j, afs[j]);
            }
        }
    }

    // --- epilogue ----------------------------------------------------------
    if constexpr (GATES) {
        // MFR == NFR == 2 (64x64 tile). Exchange acc via LDS z-tile.
        float* zs = (float*)&lds[0];          // 64*65*4 = 16.6 KB <= 48 KB
        __syncthreads();
#pragma unroll
        for (int m = 0; m < MFR; ++m)
#pragma unroll
            for (int n = 0; n < NFR; ++n)
#pragma unroll
                for (int r = 0; r < 4; ++r)
                    zs[(wm * 32 + m * 16 + lq * 4 + r) * 65 +
                       wn * 32 + n * 16 + l15] = acc[m][n][r];
        __syncthreads();

        const int row = tid & 63;
        const int jl0 = (tid >> 6) * 4;
        const int grow = m0 + row;
        const int jg = n_tile * 16 + jl0;        // h column (0..1023)
        const f32x4 bi4 = *(const f32x4*)&bias[n0 + jl0];
        const f32x4 bf4 = *(const f32x4*)&bias[n0 + 16 + jl0];
        const f32x4 bg4 = *(const f32x4*)&bias[n0 + 32 + jl0];
        const f32x4 bo4 = *(const f32x4*)&bias[n0 + 48 + jl0];
        f32x4 cv = *(f32x4*)&c[(size_t)grow * H_SZ + jg];
        ushort hh[4], hl[4];
#pragma unroll
        for (int jj = 0; jj < 4; ++jj) {
            const float zi = zs[row * 65 + jl0 + jj] + bi4[jj];
            const float zf = zs[row * 65 + 16 + jl0 + jj] + bf4[jj];
            const float zg = zs[row * 65 + 32 + jl0 + jj] + bg4[jj];
            const float zo = zs[row * 65 + 48 + jl0 + jj] + bo4[jj];
            const float ig = 1.f / (1.f + expf(-zi));
            const float fg = 1.f / (1.f + expf(-zf));
            const float gg = tanhf(zg);
            const float og = 1.f / (1.f + expf(-zo));
            const float cn = fg * cv[jj] + ig * gg;
            cv[jj] = cn;
            const float hv = og * tanhf(cn);
            hh[jj] = f2bf(hv);
            hl[jj] = f2bf(hv - bf2f(hh[jj]));
        }
        *(f32x4*)&c[(size_t)grow * H_SZ + jg] = cv;
        // fragment-major h store: hi at col hoff+jg, lo at col hoff+jg+1024.
        const int colh = hoff + jg;
        const int rt = grow >> 4;
        const int lh = (grow & 15) + (((colh >> 3) & 3) << 4);
        const size_t hb = (((size_t)rt * hkt + (colh >> 5)) * 64 + lh) * 8 + (colh & 7);
        uint hv2[2], lv2[2];
        hv2[0] = (uint)hh[0] | ((uint)hh[1] << 16);
        hv2[1] = (uint)hh[2] | ((uint)hh[3] << 16);
        lv2[0] = (uint)hl[0] | ((uint)hl[1] << 16);
        lv2[1] = (uint)hl[2] | ((uint)hl[3] << 16);
        *(uint*)&hdest[hb]         = hv2[0];
        *(uint*)&hdest[hb + 2]     = hv2[1];
        *(uint*)&hdest[hb + 16384] = lv2[0];   // +32 k-tiles (1024 cols)
        *(uint*)&hdest[hb + 16386] = lv2[1];

        if (xdest) {                            // fused x_{t+1} conversion
            const int idx = flat * 256 + tid;   // exactly B*I = 131072
            const int b = idx >> 8, i = idx & 255;
            const float v = xsrc[(size_t)b * (T_SZ * I_SZ) + i];
            const ushort hi = f2bf(v), lo = f2bf(v - bf2f(hi));
            const int rtx = b >> 4;
            const int lx = (b & 15) + (((i >> 3) & 3) << 4);
            const int e = i & 7;
            xdest[(((size_t)rtx * 80 + (i >> 5)) * 64 + lx) * 8 + e] = hi;
            xdest[(((size_t)rtx * 80 + 8 + (i >> 5)) * 64 + lx) * 8 + e] = lo;
        }
    } else {
        // MFR == NFR == 1 (32x32). Store logits; fused per-row argmax.
        float vals[4];
        const int col = n0 + wn * 16 + l15;
        const float bv = bias[col];
#pragma unroll
        for (int r = 0; r < 4; ++r) {
            const int row = m0 + wm * 16 + lq * 4 + r;
            vals[r] = acc[0][0][r] + bv;
            out[(size_t)row * ldo + col] = vals[r];
        }
        if (keys) {
            float* zs = (float*)&lds[0];        // 32*33*4 = 4.2 KB
            __syncthreads();
#pragma unroll
            for (int r = 0; r < 4; ++r)
                zs[(wm * 16 + lq * 4 + r) * 33 + wn * 16 + l15] = vals[r];
            __syncthreads();
            if (tid < 32) {
                const int row = tid;
                float best = zs[row * 33];
                int bc = 0;
#pragma unroll
                for (int cc = 1; cc < 32; ++cc) {
                    const float x = zs[row * 33 + cc];
                    if (x > best) { best = x; bc = cc; }   // strict > : earliest col
                }
                const unsigned long long key =
                    ((unsigned long long)fmono(best) << 32) |
                    (unsigned long long)(V_SZ - 1 - (n0 + bc));
                atomicMax(&keys[m0 + row], key);
            }
        }
    }
}

// ---------------------------------------------------------------------------
// Gather: argmax key -> embed row -> xc (fragment-major) of next dec A;
// reset key to 0 (same-wave read-before-write).
// ---------------------------------------------------------------------------
__global__ __launch_bounds__(256) void gather_embed(
    unsigned long long* __restrict__ keys,
    const float* __restrict__ embed_W,
    ushort* __restrict__ xdest)
{
    const int idx = blockIdx.x * 256 + threadIdx.x;   // < 4096
    const int b = idx >> 3, e = idx & 7;
    const unsigned long long key = keys[b];
    const int yb = V_SZ - 1 - (int)(key & 0xffffffffu);
    const float v = embed_W[(size_t)yb * E_SZ + e];
    const ushort hi = f2bf(v), lo = f2bf(v - bf2f(hi));
    const size_t base = (size_t)(b >> 4) * 68 * 512;   // rt * KT * 64 * 8
    const int l0 = b & 15;
    xdest[base + (size_t)(l0)      * 8 + e] = hi;      // col e
    xdest[base + (size_t)(l0 + 16) * 8 + e] = hi;      // col 8+e
    xdest[base + (size_t)(l0 + 32) * 8 + e] = lo;      // col 16+e
    if (e == 0) keys[b] = 0ull;                        // after the wave's reads
}

// ---------------------------------------------------------------------------
// Weight packing (gate-permuted rows n' = jhi*64 + g*16 + jlo), paired cols.
// (unchanged from R12)
// ---------------------------------------------------------------------------
__global__ void pack_enc(const float* __restrict__ Wih, const float* __restrict__ Whh,
                         const float* __restrict__ b, ushort* __restrict__ Wp,
                         float* __restrict__ bp)
{
    const int k = blockIdx.x * 256 + threadIdx.x;   // < 3840
    const int np = blockIdx.y;                      // < 4096
    const int orig = ((np >> 4) & 3) * H_SZ + (np >> 6) * 16 + (np & 15);
    float v; bool lo = false;
    if (k < 2560) {                                  // paired region
        const int p = k >> 7, cc = k & 63;
        lo = (k >> 6) & 1;
        v = (p < 4) ? Wih[(size_t)orig * I_SZ + p * 64 + cc]
                    : Whh[(size_t)orig * H_SZ + (p - 4) * 64 + cc];
    } else {                                         // single region (W_hi)
        const int s = (k - 2560) >> 6, cc = k & 63;
        v = (s < 4) ? Wih[(size_t)orig * I_SZ + s * 64 + cc]
                    : Whh[(size_t)orig * H_SZ + (s - 4) * 64 + cc];
    }
    const ushort hi = f2bf(v);
    Wp[(size_t)np * KVE + k] = lo ? f2bf(v - bf2f(hi)) : hi;
    if (k == 0) bp[np] = b[orig];
}

__global__ void pack_dec(const float* __restrict__ Wih, const float* __restrict__ Whh,
                         const float* __restrict__ b, ushort* __restrict__ Wp,
                         float* __restrict__ bp)
{
    const int k = blockIdx.x * 256 + threadIdx.x;
    const int np = blockIdx.y;
    if (k >= KVD) return;                            // KVD = 3200
    const int orig = ((np >> 4) & 3) * H_SZ + (np >> 6) * 16 + (np & 15);
    float v = 0.f; bool lo = false; bool zero = false;
    if (k < 2048) {                                  // paired: Whh hi|lo
        const int p = k >> 7, cc = k & 63;
        lo = (k >> 6) & 1;
        v = Whh[(size_t)orig * H_SZ + p * 64 + cc];
    } else {
        const int s = (k - 2048) >> 6, cc = k & 63;
        if (s < 2) {                                 // xc tiles (pre-expanded)
            const int j = s * 64 + cc;
            if (j < 8)       v = Wih[(size_t)orig * E_SZ + j];
            else if (j < 16) { v = Wih[(size_t)orig * E_SZ + j - 8]; lo = true; }
            else if (j < 24) v = Wih[(size_t)orig * E_SZ + j - 16];
            else             zero = true;
        } else {                                     // h_lo singles: Whh_hi
            v = Whh[(size_t)orig * H_SZ + (s - 2) * 64 + cc];
        }
    }
    ushort w = 0;
    if (!zero) { const ushort hi = f2bf(v); w = lo ? f2bf(v - bf2f(hi)) : hi; }
    Wp[(size_t)np * KVD + k] = w;
    if (k == 0) bp[np] = b[orig];
}

__global__ void pack_fc(const float* __restrict__ W, ushort* __restrict__ Wp)
{
    const int k = blockIdx.x * 256 + threadIdx.x;   // < 3072
    const int np = blockIdx.y;                      // < 1024 (no permute)
    float v; bool lo = false;
    if (k < 2048) {
        const int p = k >> 7, cc = k & 63;
        lo = (k >> 6) & 1;
        v = W[(size_t)np * H_SZ + p * 64 + cc];
    } else {
        const int s = (k - 2048) >> 6, cc = k & 63;
        v = W[(size_t)np * H_SZ + s * 64 + cc];
    }
    const ushort hi = f2bf(v);
    Wp[(size_t)np * KVF + k] = lo ? f2bf(v - bf2f(hi)) : hi;
}

// ---------------------------------------------------------------------------
// Init (fragment-major A): zero c; zero A_enc0 h region; convert x(0);
// xc(0) from embed row 0; zero dec xc pads; zero keys. Grid 512 x 256.
// ---------------------------------------------------------------------------
__global__ void init_all(const float* __restrict__ x0,
                         const float* __restrict__ embed_W,
                         float* __restrict__ c,
                         ushort* __restrict__ Aenc0,
                         ushort* __restrict__ Adec0,
                         ushort* __restrict__ Adec1,
                         unsigned long long* __restrict__ keys)
{
    const int idx = blockIdx.x * 256 + threadIdx.x;   // < 131072
    {   // zero c: 4 floats per thread (B*H = 131072*4)
        f32x4 z = {0.f, 0.f, 0.f, 0.f};
        *(f32x4*)&c[(size_t)idx * 4] = z;
    }
    {   // zero A_enc0 h region: cols 512..2559, 8 cols per thread (16B store)
        const int b = idx >> 8, g = idx & 255;
        const int col = 512 + g * 8;
        const int l = (b & 15) + (((col >> 3) & 3) << 4);
        short8 z8 = {};
        *(short8*)&Aenc0[(((size_t)(b >> 4) * 80 + (col >> 5)) * 64 + l) * 8] = z8;
    }
    {   // x(0) hi/lo (cols i, 256+i) -- disjoint from h region above
        const int b = idx >> 8, i = idx & 255;
        const float v = x0[(size_t)b * (T_SZ * I_SZ) + i];
        const ushort hi = f2bf(v), lo = f2bf(v - bf2f(hi));
        const int l = (b & 15) + (((i >> 3) & 3) << 4);
        const int e = i & 7;
        Aenc0[(((size_t)(b >> 4) * 80 + (i >> 5)) * 64 + l) * 8 + e] = hi;
        Aenc0[(((size_t)(b >> 4) * 80 + 8 + (i >> 5)) * 64 + l) * 8 + e] = lo;
    }
    if (idx < B_SZ) keys[idx] = 0ull;
    if (idx < B_SZ * 104) {   // dec xc pads: cols 24..127, both buffers
        const int b = idx / 104, col = 24 + idx % 104;
        const int l = (b & 15) + (((col >> 3) & 3) << 4);
        const size_t o = (((size_t)(b >> 4) * 68 + (col >> 5)) * 64 + l) * 8 + (col & 7);
        Adec0[o] = 0;
        Adec1[o] = 0;
    }
    if (idx < B_SZ * 24) {    // xc(0) from embed row 0: cols 0..23 (kt = 0)
        const int b = idx / 24, col = idx % 24;
        float v;
        if (col < 8)       v = embed_W[col];
        else if (col < 16) v = embed_W[col - 8];
        else               v = embed_W[col - 16];
        const ushort hi = f2bf(v);
        const ushort w = (col < 16) ? hi : f2bf(v - bf2f(hi));
        const int l = (b & 15) + ((col >> 3) << 4);
        Adec0[((size_t)(b >> 4) * 68 * 64 + l) * 8 + (col & 7)] = w;
    }
}

extern "C" void kernel_launch(void* const* d_in, const int* in_sizes, int n_in,
                              void* d_out, int out_size, void* d_ws, size_t ws_size,
                              hipStream_t stream)
{
    const float* x_hist  = (const float*)d_in[0];
    const float* enc_Wih = (const float*)d_in[1];
    const float* enc_Whh = (const float*)d_in[2];
    const float* enc_b   = (const float*)d_in[3];
    const float* embed_W = (const float*)d_in[4];
    const float* dec_Wih = (const float*)d_in[5];
    const float* dec_Whh = (const float*)d_in[6];
    const float* dec_b   = (const float*)d_in[7];
    const float* fc_W    = (const float*)d_in[8];
    const float* fc_b    = (const float*)d_in[9];
    float* out = (float*)d_out;

    char* p = (char*)d_ws;
    auto alloc = [&](size_t bytes) {
        char* r = p;
        p += (bytes + 255) & ~(size_t)255;
        return r;
    };
    ushort* W_enc  = (ushort*)alloc((size_t)4096 * KVE * 2);   // 30 MB
    ushort* W_dec  = (ushort*)alloc((size_t)4096 * KVD * 2);   // 25 MB
    ushort* W_fc   = (ushort*)alloc((size_t)1024 * KVF * 2);   // 6 MB
    ushort* A_enc0 = (ushort*)alloc((size_t)B_SZ * APE * 2);   // 2.5 MB
    ushort* A_enc1 = (ushort*)alloc((size_t)B_SZ * APE * 2);
    ushort* A_dec0 = (ushort*)alloc((size_t)B_SZ * APD * 2);   // 2.13 MB
    ushort* A_dec1 = (ushort*)alloc((size_t)B_SZ * APD * 2);
    float*  cbuf   = (float*)alloc((size_t)B_SZ * H_SZ * 4);   // 2 MB
    float*  bpe    = (float*)alloc(4096 * 4);
    float*  bpd    = (float*)alloc(4096 * 4);
    unsigned long long* keys = (unsigned long long*)alloc(B_SZ * 8);

    const dim3 blk(256);
    hipLaunchKernelGGL(pack_enc, dim3(15, 4096), blk, 0, stream, enc_Wih, enc_Whh, enc_b, W_enc, bpe);
    hipLaunchKernelGGL(pack_dec, dim3(13, 4096), blk, 0, stream, dec_Wih, dec_Whh, dec_b, W_dec, bpd);
    hipLaunchKernelGGL(pack_fc,  dim3(12, 1024), blk, 0, stream, fc_W, W_fc);
    hipLaunchKernelGGL(init_all, dim3(512), blk, 0, stream, x_hist, embed_W, cbuf, A_enc0, A_dec0, A_dec1, keys);

    ushort* Ae[2] = {A_enc0, A_enc1};
    ushort* Ad[2] = {A_dec0, A_dec1};

    // Encoder. Paired p: A col = 64p + (p<4 ? 0 : 256)  [x_hi, h_hi]
    //          Single s: A col = 64s + (s<4 ? 256 : 1280) [x_lo, h_lo]
    for (int t = 0; t < T_SZ; ++t) {
        ushort* hdst; int hoff, hkt; const float* xs; ushort* xd;
        if (t < T_SZ - 1) {
            hdst = Ae[(t + 1) & 1]; hoff = 512; hkt = 80;
            xs = x_hist + (size_t)(t + 1) * I_SZ;
            xd = Ae[(t + 1) & 1];
        } else {
            hdst = Ad[0]; hoff = 128; hkt = 68;
            xs = nullptr; xd = nullptr;
        }
        hipLaunchKernelGGL((gemm_step<2, 2, 8, 20, 4, 0, 256, 20, 4, 256, 1280, true>),
                           dim3(512), blk, 0, stream,
                           Ae[t & 1], APE, W_enc, KVE, bpe, cbuf,
                           hdst, hoff, hkt, xs, xd, (float*)nullptr, 0,
                           (unsigned long long*)nullptr);
    }

    // Decoder. Paired p: A col = 64p + 128 [h_hi].
    //          Single s: A col = 64s + (s<2 ? 0 : 1024) [xc, h_lo].
    // fc:      Paired p: A col = 64p + 128 [h_hi]; Single s: 64s + 1152 [h_lo].
    for (int t = 0; t < FUT; ++t) {
        hipLaunchKernelGGL((gemm_step<2, 2, 8, 16, 16, 128, 128, 18, 2, 0, 1024, true>),
                           dim3(512), blk, 0, stream,
                           Ad[t & 1], APD, W_dec, KVD, bpd, cbuf,
                           Ad[(t + 1) & 1], 128, 68,
                           (const float*)nullptr, (ushort*)nullptr,
                           (float*)nullptr, 0,
                           (unsigned long long*)nullptr);
        float* logits = out + (size_t)t * V_SZ;   // [B, FUT, V]
        hipLaunchKernelGGL((gemm_step<1, 1, 4, 16, 16, 128, 128, 16, 16, 1152, 1152, false>),
                           dim3(512), blk, 0, stream,
                           Ad[(t + 1) & 1], APD, W_fc, KVF, fc_b,
                           (float*)nullptr, (ushort*)nullptr, 0, 0,
                           (const float*)nullptr, (ushort*)nullptr,
                           logits, FUT * V_SZ, keys);
        hipLaunchKernelGGL(gather_embed, dim3(16), blk, 0, stream,
                           keys, embed_W, Ad[(t + 1) & 1]);
    }
}

// Round 16
// 9755.086 us; speedup vs baseline: 1.5481x; 1.5481x over previous
//
#include <hip/hip_runtime.h>
#include <cmath>

typedef __attribute__((ext_vector_type(8))) short short8;
typedef __attribute__((ext_vector_type(4))) float f32x4;

#define B_SZ 512
#define T_SZ 256
#define I_SZ 256
#define H_SZ 1024
#define V_SZ 1024
#define E_SZ 8
#define FUT 64

// R5 numerics (3 products: A_hi*W_hi + A_hi*W_lo + A_lo*W_hi), paired layout:
// A phys:
//   enc: [x_hi 256 | x_lo 256 | h_hi 1024 | h_lo 1024] = 2560
//   dec: [xc 128 (x_hi8|x_hi8|x_lo8|0) | h_hi 1024 | h_lo 1024] = 2176
// W packed, two regions:
//   paired: per hi-A-seg p (64 cols): [W_hi(seg p) 64 | W_lo(seg p) 64]
//   single: per lo-A-seg s: [W_hi(seg s) 64]   (+ dec xc pre-expanded tiles)
#define KVE 3840
#define KVD 3200
#define KVF 3072
#define APE 2560
#define APD 2176

static __device__ __forceinline__ ushort f2bf(float v) {
    uint32_t u = __float_as_uint(v);
    uint32_t r = (u + 0x7fffu + ((u >> 16) & 1u)) >> 16;
    return (ushort)r;
}
static __device__ __forceinline__ float bf2f(ushort b) {
    return __uint_as_float(((uint32_t)b) << 16);
}
// Monotone float->uint mapping: a > b  <=>  map(a) > map(b) (finite floats).
static __device__ __forceinline__ uint32_t fmono(float f) {
    uint32_t u = __float_as_uint(f);
    return (u & 0x80000000u) ? ~u : (u | 0x80000000u);
}
template<int N>
static __device__ __forceinline__ void waitvm() {
    if constexpr (N == 0)      asm volatile("s_waitcnt vmcnt(0)" ::: "memory");
    else if constexpr (N == 2) asm volatile("s_waitcnt vmcnt(2)" ::: "memory");
    else if constexpr (N == 3) asm volatile("s_waitcnt vmcnt(3)" ::: "memory");
    else if constexpr (N == 4) asm volatile("s_waitcnt vmcnt(4)" ::: "memory");
    else if constexpr (N == 6) asm volatile("s_waitcnt vmcnt(6)" ::: "memory");
}

#define GLD16(gp, lp)                                                          \
    __builtin_amdgcn_global_load_lds(                                         \
        (const __attribute__((address_space(1))) void*)(gp),                  \
        (__attribute__((address_space(3))) void*)(lp), 16, 0, 0)

// ---------------------------------------------------------------------------
// Paired split-bf16 GEMM step (R12/R14 verified core). Block (MFR*32) x
// (NFR*32), 4 waves (2m x 2n). Paired tiles reuse af registers across the
// W_hi/W_lo subtiles; 3 rotating LDS buffers; counted-vmcnt pipeline (stage
// i+2 while computing i; wait leaves only group(i+1) outstanding).
// DECXC=true (dec lstm): prologue writes this block's m-tile xc rows of the
// INPUT A buffer from the argmax key buffer + embedding (replaces the old
// gather_embed kernel), and flat==0 zeroes the key slot fc(t+1) will use.
// The first counted waitvm drains these stores before any stage reads xc.
// ---------------------------------------------------------------------------
template<int MFR, int NFR, int NTPX,
         int NKP, int PT1, int PO0, int PO1,
         int NKS, int ST1, int SO0, int SO1, bool GATES, bool DECXC>
__global__ __launch_bounds__(256) void gemm_step(
    const ushort* __restrict__ A, int astr,
    const ushort* __restrict__ W, int kv,
    const float* __restrict__ bias,
    float* __restrict__ c,
    ushort* __restrict__ hdest, int ldh,
    const float* __restrict__ xsrc, ushort* __restrict__ xdest,
    float* __restrict__ out, int ldo,
    unsigned long long* __restrict__ keys,
    const unsigned long long* __restrict__ kread,
    unsigned long long* __restrict__ kzero,
    const float* __restrict__ embW)
{
    constexpr int ABUF = MFR * 2048;             // ushorts per A buffer
    constexpr int WBUF = NFR * 4096;             // ushorts per W buffer (pair)
    __shared__ __align__(16) ushort lds[3 * ABUF + 3 * WBUF];

    const int tid = threadIdx.x;
    const int lane = tid & 63;
    const int wid = tid >> 6;
    const int wm = wid >> 1, wn = wid & 1;
    const int l15 = lane & 15, lq = lane >> 4;
    const int l7 = lane & 7, l3 = lane >> 3;

    const int flat = blockIdx.x;
    const int xcd = flat & 7, slot = flat >> 3;
    const int n_tile = xcd * NTPX + (slot % NTPX);
    const int m_tile = slot / NTPX;
    const int m0 = m_tile * (MFR * 32);
    const int n0 = n_tile * (NFR * 32);

    if constexpr (DECXC) {
        // Prologue: xc rows of this block's m-tile (idempotent across blocks
        // sharing m_tile -- identical values). xdest == input A buffer.
        if (tid < 192) {
            const int row = tid & 63, trip = tid >> 6;    // 0..2
            const int grow = m0 + row;
            const int yb = V_SZ - 1 - (int)(kread[grow] & 0xffffffffu);
            short8 v8;
#pragma unroll
            for (int e = 0; e < 8; ++e) {
                const float v = embW[(size_t)yb * E_SZ + e];
                const ushort hi = f2bf(v);
                v8[e] = (short)(trip < 2 ? hi : f2bf(v - bf2f(hi)));
            }
            *(short8*)&xdest[(size_t)grow * astr + trip * 8] = v8;
        }
        if (flat == 0) {                // zero the slot fc(t+1) will write
            kzero[tid] = 0ull;
            kzero[tid + 256] = 0ull;
        }
    }

    f32x4 acc[MFR][NFR];
#pragma unroll
    for (int m = 0; m < MFR; ++m)
#pragma unroll
        for (int n = 0; n < NFR; ++n) { f32x4 z = {0.f, 0.f, 0.f, 0.f}; acc[m][n] = z; }

    auto stageA = [&](int kcA, int bufi) {
        ushort* ab = &lds[bufi * ABUF];
#pragma unroll
        for (int i = 0; i < MFR; ++i) {
            const int rowg = (i * 4 + wid) * 8;
            const int row = rowg + l3;
            GLD16(A + (size_t)(m0 + row) * astr + kcA + ((l7 ^ (row & 7)) * 8),
                  ab + rowg * 64);
        }
    };
    auto stageP = [&](int p, int bufi) {
        stageA(p * 64 + (p < PT1 ? PO0 : PO1), bufi);
        const int kcW = p * 128;
        ushort* wb = &lds[3 * ABUF + bufi * WBUF];
#pragma unroll
        for (int i = 0; i < 2 * NFR; ++i) {      // 256B rows, 16 lanes/row
            const int rowg = (i * 4 + wid) * 4;
            const int row = rowg + lq;
            GLD16(W + (size_t)(n0 + row) * kv + kcW + ((l15 ^ (row & 15)) * 8),
                  wb + rowg * 128);
        }
    };
    auto stageS = [&](int s, int bufi) {
        stageA(s * 64 + (s < ST1 ? SO0 : SO1), bufi);
        const int kcW = NKP * 128 + s * 64;
        ushort* wb = &lds[3 * ABUF + bufi * WBUF];
#pragma unroll
        for (int i = 0; i < NFR; ++i) {          // 128B rows
            const int rowg = (i * 4 + wid) * 8;
            const int row = rowg + l3;
            GLD16(W + (size_t)(n0 + row) * kv + kcW + ((l7 ^ (row & 7)) * 8),
                  wb + rowg * 64);
        }
    };
    auto compP = [&](int bufi) {
        const ushort* ab = &lds[bufi * ABUF];
        const ushort* wb = &lds[3 * ABUF + bufi * WBUF];
#pragma unroll
        for (int kk = 0; kk < 2; ++kk) {
            short8 af[MFR];
#pragma unroll
            for (int m = 0; m < MFR; ++m) {
                const int row = wm * (MFR * 16) + m * 16 + l15;
                af[m] = *(const short8*)
                    &ab[row * 64 + (((kk * 4 + lq) ^ (row & 7)) * 8)];
            }
#pragma unroll
            for (int sub = 0; sub < 2; ++sub) {
                short8 wf[NFR];
#pragma unroll
                for (int n = 0; n < NFR; ++n) {
                    const int row = wn * (NFR * 16) + n * 16 + l15;
                    wf[n] = *(const short8*)
                        &wb[row * 128 + (((sub * 8 + kk * 4 + lq) ^ (row & 15)) * 8)];
                }
#pragma unroll
                for (int m = 0; m < MFR; ++m)
#pragma unroll
                    for (int n = 0; n < NFR; ++n)
                        acc[m][n] = __builtin_amdgcn_mfma_f32_16x16x32_bf16(
                            af[m], wf[n], acc[m][n], 0, 0, 0);
            }
        }
    };
    auto compS = [&](int bufi) {
        const ushort* ab = &lds[bufi * ABUF];
        const ushort* wb = &lds[3 * ABUF + bufi * WBUF];
#pragma unroll
        for (int kk = 0; kk < 2; ++kk) {
            short8 af[MFR], wf[NFR];
#pragma unroll
            for (int m = 0; m < MFR; ++m) {
                const int row = wm * (MFR * 16) + m * 16 + l15;
                af[m] = *(const short8*)
                    &ab[row * 64 + (((kk * 4 + lq) ^ (row & 7)) * 8)];
            }
#pragma unroll
            for (int n = 0; n < NFR; ++n) {
                const int row = wn * (NFR * 16) + n * 16 + l15;
                wf[n] = *(const short8*)
                    &wb[row * 64 + (((kk * 4 + lq) ^ (row & 7)) * 8)];
            }
#pragma unroll
            for (int m = 0; m < MFR; ++m)
#pragma unroll
                for (int n = 0; n < NFR; ++n)
                    acc[m][n] = __builtin_amdgcn_mfma_f32_16x16x32_bf16(
                        af[m], wf[n], acc[m][n], 0, 0, 0);
        }
    };

    auto STG = [&](int i, int b) { if (i < NKP) stageP(i, b); else stageS(i - NKP, b); };

    constexpr int NT = NKP + NKS;
    constexpr int GP = MFR + 2 * NFR;            // gld/wave of a paired stage
    constexpr int GS = MFR + NFR;                // gld/wave of a single stage

    STG(0, 0);
    STG(1, 1);
#pragma unroll 1
    for (int i0 = 0; i0 < NT; i0 += 3) {
#pragma unroll
        for (int j = 0; j < 3; ++j) {
            const int i = i0 + j;
            if (i < NT) {
                // wait: stage i complete; outstanding = stage i+1 only.
                // (Prologue stores are older than STG(0) -> also drained.)
                if (i + 1 < NKP)     waitvm<GP>();
                else if (i + 1 < NT) waitvm<GS>();
                else                 waitvm<0>();
                __builtin_amdgcn_s_barrier();
                if (i + 2 < NT) STG(i + 2, (j + 2) % 3);
                if (i < NKP) compP(j); else compS(j);
            }
        }
    }

    // --- epilogue ----------------------------------------------------------
    if constexpr (GATES) {
        // MFR == NFR == 2 (64x64 tile). Exchange acc via LDS z-tile.
        float* zs = (float*)&lds[0];          // 64*65*4 = 16.6 KB
        __syncthreads();
#pragma unroll
        for (int m = 0; m < MFR; ++m)
#pragma unroll
            for (int n = 0; n < NFR; ++n)
#pragma unroll
                for (int r = 0; r < 4; ++r)
                    zs[(wm * 32 + m * 16 + lq * 4 + r) * 65 +
                       wn * 32 + n * 16 + l15] = acc[m][n][r];
        __syncthreads();

        const int row = tid & 63;
        const int jl0 = (tid >> 6) * 4;
        const int grow = m0 + row;
        const int jg = n_tile * 16 + jl0;
        const f32x4 bi4 = *(const f32x4*)&bias[n0 + jl0];
        const f32x4 bf4 = *(const f32x4*)&bias[n0 + 16 + jl0];
        const f32x4 bg4 = *(const f32x4*)&bias[n0 + 32 + jl0];
        const f32x4 bo4 = *(const f32x4*)&bias[n0 + 48 + jl0];
        f32x4 cv = *(f32x4*)&c[(size_t)grow * H_SZ + jg];
        ushort hh[4], hl[4];
#pragma unroll
        for (int jj = 0; jj < 4; ++jj) {
            const float zi = zs[row * 65 + jl0 + jj] + bi4[jj];
            const float zf = zs[row * 65 + 16 + jl0 + jj] + bf4[jj];
            const float zg = zs[row * 65 + 32 + jl0 + jj] + bg4[jj];
            const float zo = zs[row * 65 + 48 + jl0 + jj] + bo4[jj];
            const float ig = 1.f / (1.f + expf(-zi));
            const float fg = 1.f / (1.f + expf(-zf));
            const float gg = tanhf(zg);
            const float og = 1.f / (1.f + expf(-zo));
            const float cn = fg * cv[jj] + ig * gg;
            cv[jj] = cn;
            const float hv = og * tanhf(cn);
            hh[jj] = f2bf(hv);
            hl[jj] = f2bf(hv - bf2f(hh[jj]));
        }
        *(f32x4*)&c[(size_t)grow * H_SZ + jg] = cv;
        ushort* hd = hdest + (size_t)grow * ldh + jg;
        uint hv2[2], lv2[2];
        hv2[0] = (uint)hh[0] | ((uint)hh[1] << 16);
        hv2[1] = (uint)hh[2] | ((uint)hh[3] << 16);
        lv2[0] = (uint)hl[0] | ((uint)hl[1] << 16);
        lv2[1] = (uint)hl[2] | ((uint)hl[3] << 16);
        *(uint*)&hd[0] = hv2[0];
        *(uint*)&hd[2] = hv2[1];
        *(uint*)&hd[1024] = lv2[0];
        *(uint*)&hd[1026] = lv2[1];            // h_lo always hi_base + 1024

        if constexpr (!DECXC) {
            if (xdest) {                        // fused x_{t+1} conversion (enc)
                const int idx = flat * 256 + tid;   // exactly B*I = 131072
                const int b = idx >> 8, i = idx & 255;
                const float v = xsrc[(size_t)b * (T_SZ * I_SZ) + i];
                const ushort hi = f2bf(v), lo = f2bf(v - bf2f(hi));
                xdest[(size_t)b * APE + i] = hi;
                xdest[(size_t)b * APE + 256 + i] = lo;
            }
        }
    } else {
        // MFR == NFR == 1 (32x32). Store logits; fused per-row argmax.
        float vals[4];
        const int col = n0 + wn * 16 + l15;
        const float bv = bias[col];
#pragma unroll
        for (int r = 0; r < 4; ++r) {
            const int row = m0 + wm * 16 + lq * 4 + r;
            vals[r] = acc[0][0][r] + bv;
            out[(size_t)row * ldo + col] = vals[r];
        }
        if (keys) {
            float* zs = (float*)&lds[0];        // 32*33*4 = 4.2 KB
            __syncthreads();
#pragma unroll
            for (int r = 0; r < 4; ++r)
                zs[(wm * 16 + lq * 4 + r) * 33 + wn * 16 + l15] = vals[r];
            __syncthreads();
            if (tid < 32) {
                const int row = tid;
                float best = zs[row * 33];
                int bc = 0;
#pragma unroll
                for (int cc = 1; cc < 32; ++cc) {
                    const float x = zs[row * 33 + cc];
                    if (x > best) { best = x; bc = cc; }   // strict > : earliest col
                }
                const unsigned long long key =
                    ((unsigned long long)fmono(best) << 32) |
                    (unsigned long long)(V_SZ - 1 - (n0 + bc));
                atomicMax(&keys[m0 + row], key);
            }
        }
    }
}

// ---------------------------------------------------------------------------
// Weight packing (gate-permuted rows n' = jhi*64 + g*16 + jlo), paired cols.
// ---------------------------------------------------------------------------
__global__ void pack_enc(const float* __restrict__ Wih, const float* __restrict__ Whh,
                         const float* __restrict__ b, ushort* __restrict__ Wp,
                         float* __restrict__ bp)
{
    const int k = blockIdx.x * 256 + threadIdx.x;   // < 3840
    const int np = blockIdx.y;                      // < 4096
    const int orig = ((np >> 4) & 3) * H_SZ + (np >> 6) * 16 + (np & 15);
    float v; bool lo = false;
    if (k < 2560) {                                  // paired region
        const int p = k >> 7, cc = k & 63;
        lo = (k >> 6) & 1;
        v = (p < 4) ? Wih[(size_t)orig * I_SZ + p * 64 + cc]
                    : Whh[(size_t)orig * H_SZ + (p - 4) * 64 + cc];
    } else {                                         // single region (W_hi)
        const int s = (k - 2560) >> 6, cc = k & 63;
        v = (s < 4) ? Wih[(size_t)orig * I_SZ + s * 64 + cc]
                    : Whh[(size_t)orig * H_SZ + (s - 4) * 64 + cc];
    }
    const ushort hi = f2bf(v);
    Wp[(size_t)np * KVE + k] = lo ? f2bf(v - bf2f(hi)) : hi;
    if (k == 0) bp[np] = b[orig];
}

__global__ void pack_dec(const float* __restrict__ Wih, const float* __restrict__ Whh,
                         const float* __restrict__ b, ushort* __restrict__ Wp,
                         float* __restrict__ bp)
{
    const int k = blockIdx.x * 256 + threadIdx.x;
    const int np = blockIdx.y;
    if (k >= KVD) return;                            // KVD = 3200
    const int orig = ((np >> 4) & 3) * H_SZ + (np >> 6) * 16 + (np & 15);
    float v = 0.f; bool lo = false; bool zero = false;
    if (k < 2048) {                                  // paired: Whh hi|lo
        const int p = k >> 7, cc = k & 63;
        lo = (k >> 6) & 1;
        v = Whh[(size_t)orig * H_SZ + p * 64 + cc];
    } else {
        const int s = (k - 2048) >> 6, cc = k & 63;
        if (s < 2) {                                 // xc tiles (pre-expanded)
            const int j = s * 64 + cc;
            if (j < 8)       v = Wih[(size_t)orig * E_SZ + j];
            else if (j < 16) { v = Wih[(size_t)orig * E_SZ + j - 8]; lo = true; }
            else if (j < 24) v = Wih[(size_t)orig * E_SZ + j - 16];
            else             zero = true;
        } else {                                     // h_lo singles: Whh_hi
            v = Whh[(size_t)orig * H_SZ + (s - 2) * 64 + cc];
        }
    }
    ushort w = 0;
    if (!zero) { const ushort hi = f2bf(v); w = lo ? f2bf(v - bf2f(hi)) : hi; }
    Wp[(size_t)np * KVD + k] = w;
    if (k == 0) bp[np] = b[orig];
}

__global__ void pack_fc(const float* __restrict__ W, ushort* __restrict__ Wp)
{
    const int k = blockIdx.x * 256 + threadIdx.x;   // < 3072
    const int np = blockIdx.y;                      // < 1024 (no permute)
    float v; bool lo = false;
    if (k < 2048) {
        const int p = k >> 7, cc = k & 63;
        lo = (k >> 6) & 1;
        v = W[(size_t)np * H_SZ + p * 64 + cc];
    } else {
        const int s = (k - 2048) >> 6, cc = k & 63;
        v = W[(size_t)np * H_SZ + s * 64 + cc];
    }
    const ushort hi = f2bf(v);
    Wp[(size_t)np * KVF + k] = lo ? f2bf(v - bf2f(hi)) : hi;
}

// ---------------------------------------------------------------------------
// Init: zero c + A_enc0 h region; convert x(0); zero dec xc pads (both
// buffers); key slots: kb[0]=kb[1]=0, kb[2] seeded with y=0 keys.
// ---------------------------------------------------------------------------
__global__ void init_all(const float* __restrict__ x0,
                         float* __restrict__ c,
                         ushort* __restrict__ Aenc0,
                         ushort* __restrict__ Adec0,
                         ushort* __restrict__ Adec1,
                         unsigned long long* __restrict__ kb)
{
    const int idx = blockIdx.x * 256 + threadIdx.x;   // < 512*2048
    {
        const int b = idx >> 11, k = idx & 2047;
        Aenc0[(size_t)b * APE + 512 + k] = 0;
    }
    if (idx < B_SZ * H_SZ) c[idx] = 0.f;
    if (idx < B_SZ) {
        kb[idx] = 0ull;                                // slot 0
        kb[512 + idx] = 0ull;                          // slot 1
        kb[1024 + idx] = 1023ull;                      // slot 2: yb = 1023-1023 = 0
    }
    if (idx < B_SZ * I_SZ) {
        const int b = idx >> 8, i = idx & 255;
        const float v = x0[(size_t)b * (T_SZ * I_SZ) + i];
        const ushort hi = f2bf(v), lo = f2bf(v - bf2f(hi));
        Aenc0[(size_t)b * APE + i] = hi;
        Aenc0[(size_t)b * APE + 256 + i] = lo;
    }
    if (idx < B_SZ * 104) {
        const int b = idx / 104, col = 24 + idx % 104;
        Adec0[(size_t)b * APD + col] = 0;
        Adec1[(size_t)b * APD + col] = 0;
    }
}

extern "C" void kernel_launch(void* const* d_in, const int* in_sizes, int n_in,
                              void* d_out, int out_size, void* d_ws, size_t ws_size,
                              hipStream_t stream)
{
    const float* x_hist  = (const float*)d_in[0];
    const float* enc_Wih = (const float*)d_in[1];
    const float* enc_Whh = (const float*)d_in[2];
    const float* enc_b   = (const float*)d_in[3];
    const float* embed_W = (const float*)d_in[4];
    const float* dec_Wih = (const float*)d_in[5];
    const float* dec_Whh = (const float*)d_in[6];
    const float* dec_b   = (const float*)d_in[7];
    const float* fc_W    = (const float*)d_in[8];
    const float* fc_b    = (const float*)d_in[9];
    float* out = (float*)d_out;

    char* p = (char*)d_ws;
    auto alloc = [&](size_t bytes) {
        char* r = p;
        p += (bytes + 255) & ~(size_t)255;
        return r;
    };
    ushort* W_enc  = (ushort*)alloc((size_t)4096 * KVE * 2);   // 30 MB
    ushort* W_dec  = (ushort*)alloc((size_t)4096 * KVD * 2);   // 25 MB
    ushort* W_fc   = (ushort*)alloc((size_t)1024 * KVF * 2);   // 6 MB
    ushort* A_enc0 = (ushort*)alloc((size_t)B_SZ * APE * 2);   // 2.5 MB
    ushort* A_enc1 = (ushort*)alloc((size_t)B_SZ * APE * 2);
    ushort* A_dec0 = (ushort*)alloc((size_t)B_SZ * APD * 2);   // 2.13 MB
    ushort* A_dec1 = (ushort*)alloc((size_t)B_SZ * APD * 2);
    float*  cbuf   = (float*)alloc((size_t)B_SZ * H_SZ * 4);   // 2 MB
    float*  bpe    = (float*)alloc(4096 * 4);
    float*  bpd    = (float*)alloc(4096 * 4);
    unsigned long long* kb = (unsigned long long*)alloc(3 * B_SZ * 8);

    const dim3 blk(256);
    hipLaunchKernelGGL(pack_enc, dim3(15, 4096), blk, 0, stream, enc_Wih, enc_Whh, enc_b, W_enc, bpe);
    hipLaunchKernelGGL(pack_dec, dim3(13, 4096), blk, 0, stream, dec_Wih, dec_Whh, dec_b, W_dec, bpd);
    hipLaunchKernelGGL(pack_fc,  dim3(12, 1024), blk, 0, stream, fc_W, W_fc);
    hipLaunchKernelGGL(init_all, dim3(4096), blk, 0, stream, x_hist, cbuf, A_enc0, A_dec0, A_dec1, kb);

    ushort* Ae[2] = {A_enc0, A_enc1};
    ushort* Ad[2] = {A_dec0, A_dec1};
    unsigned long long* knull = nullptr;

    // Encoder. Paired p: A col = 64p + (p<4 ? 0 : 256)  [x_hi, h_hi]
    //          Single s: A col = 64s + (s<4 ? 256 : 1280) [x_lo, h_lo]
    for (int t = 0; t < T_SZ; ++t) {
        ushort* hdst; int ldh; const float* xs; ushort* xd;
        if (t < T_SZ - 1) {
            hdst = Ae[(t + 1) & 1] + 512; ldh = APE;
            xs = x_hist + (size_t)(t + 1) * I_SZ;
            xd = Ae[(t + 1) & 1];
        } else {
            hdst = Ad[0] + 128; ldh = APD;
            xs = nullptr; xd = nullptr;
        }
        hipLaunchKernelGGL((gemm_step<2, 2, 8, 20, 4, 0, 256, 20, 4, 256, 1280, true, false>),
                           dim3(512), blk, 0, stream,
                           Ae[t & 1], APE, W_enc, KVE, bpe, cbuf,
                           hdst, ldh, xs, xd, (float*)nullptr, 0,
                           knull, (const unsigned long long*)nullptr, knull,
                           (const float*)nullptr);
    }

    // Decoder. Paired p: A col = 64p + 128 [h_hi].
    //          Single s: A col = 64s + (s<2 ? 0 : 1024) [xc, h_lo].
    // fc:      Paired p: A col = 64p + 128 [h_hi]; Single s: 64s + 1152 [h_lo].
    // Keys rotate: fc(t) -> kb[t%3]; lstm(t) reads kb[(t+2)%3], zeroes kb[(t+1)%3].
    for (int t = 0; t < FUT; ++t) {
        hipLaunchKernelGGL((gemm_step<2, 2, 8, 16, 16, 128, 128, 18, 2, 0, 1024, true, true>),
                           dim3(512), blk, 0, stream,
                           Ad[t & 1], APD, W_dec, KVD, bpd, cbuf,
                           Ad[(t + 1) & 1] + 128, APD,
                           (const float*)nullptr, Ad[t & 1],
                           (float*)nullptr, 0,
                           knull,
                           kb + ((t + 2) % 3) * B_SZ,
                           kb + ((t + 1) % 3) * B_SZ,
                           embed_W);
        float* logits = out + (size_t)t * V_SZ;   // [B, FUT, V]
        hipLaunchKernelGGL((gemm_step<1, 1, 4, 16, 16, 128, 128, 16, 16, 1152, 1152, false, false>),
                           dim3(512), blk, 0, stream,
                           Ad[(t + 1) & 1], APD, W_fc, KVF, fc_b,
                           (float*)nullptr, (ushort*)nullptr, 0,
                           (const float*)nullptr, (ushort*)nullptr,
                           logits, FUT * V_SZ,
                           kb + (t % 3) * B_SZ,
                           (const unsigned long long*)nullptr, knull,
                           (const float*)nullptr);
    }
}